// Round 13
// baseline (531.190 us; speedup 1.0000x reference)
//
#include <hip/hip_runtime.h>
#include <math.h>

constexpr int HID = 256;

typedef __attribute__((ext_vector_type(8))) short bf16x8;
typedef __attribute__((ext_vector_type(4))) float f32x4;

__device__ __forceinline__ float bf2f(unsigned short u){
    union { unsigned int i; float f; } v; v.i = ((unsigned int)u) << 16; return v.f;
}
__device__ __forceinline__ unsigned short f2bf(float f){
    union { float f; unsigned int i; } v; v.f = f;
    return (unsigned short)((v.i + 0x7fffu + ((v.i >> 16) & 1u)) >> 16);
}
__device__ __forceinline__ float sigm(float x){ return 1.f / (1.f + __expf(-x)); }

// bijective XCD-chunked swizzle (m204): consecutive ORIG ids land on the same XCD.
__device__ __forceinline__ int xcd_chunk(int bid, int nwg){
    int q = nwg >> 3, r = nwg & 7;
    int xcd = bid & 7, pos = bid >> 3;
    return (xcd < r) ? xcd * (q + 1) + pos : r * (q + 1) + (xcd - r) * q + pos;
}

// async global->LDS, 16B per lane. LDS dest is wave-uniform base; HW adds lane*16.
__device__ __forceinline__ void gll16(const unsigned short* g, unsigned short* l){
    __builtin_amdgcn_global_load_lds(
        (const __attribute__((address_space(1))) void*)g,
        (__attribute__((address_space(3))) void*)l, 16, 0, 0);
}

// ---------------- merged: weight casts + embedding gather + degree histogram ----------------
__global__ void k_prep(const float* __restrict__ Wproj, const float* __restrict__ Wih,
                       const float* __restrict__ Whh, const float* __restrict__ Wg,
                       const float* __restrict__ embed, const int* __restrict__ idx,
                       const int* __restrict__ edst, int E, int* __restrict__ deg,
                       unsigned short* __restrict__ wproj, unsigned short* __restrict__ wih,
                       unsigned short* __restrict__ whh, unsigned short* __restrict__ wg,
                       unsigned short* __restrict__ x0, int Nn, int EMB){
    const long n1 = (long)HID * EMB, n2 = 3L * HID * HID;
    const long n5 = (long)Nn * EMB;
    const long tot = n1 + 3 * n2 + n5 + E;
    for (long i = blockIdx.x * (long)blockDim.x + threadIdx.x; i < tot;
         i += (long)gridDim.x * blockDim.x){
        long j = i;
        if (j < n1){ wproj[j] = f2bf(Wproj[j]); continue; }
        j -= n1;
        if (j < n2){ wih[j] = f2bf(Wih[j]); continue; }
        j -= n2;
        if (j < n2){ whh[j] = f2bf(Whh[j]); continue; }
        j -= n2;
        if (j < n2){ wg[j] = f2bf(Wg[j]); continue; }
        j -= n2;
        if (j < n5){
            int row = (int)(j / EMB), k = (int)(j % EMB);
            x0[j] = f2bf(embed[(size_t)idx[row] * EMB + k]);
            continue;
        }
        j -= n5;
        atomicAdd(&deg[edst[j]], 1);
    }
}

// 3-phase parallel scan
__global__ void k_scanA(const int* __restrict__ deg, int N, int* __restrict__ bsum){
    __shared__ int red[512];
    int b = blockIdx.x, tid = threadIdx.x;
    int i = b * 512 + tid;
    red[tid] = (i < N) ? deg[i] : 0;
    __syncthreads();
    for (int o = 256; o > 0; o >>= 1){
        if (tid < o) red[tid] += red[tid + o];
        __syncthreads();
    }
    if (tid == 0) bsum[b] = red[0];
}

__global__ void k_scanB(int* __restrict__ bsum, int nb){
    __shared__ int s[1024];
    int tid = threadIdx.x;
    s[tid] = (tid < nb) ? bsum[tid] : 0;
    __syncthreads();
    for (int o = 1; o < 1024; o <<= 1){
        int v = (tid >= o) ? s[tid - o] : 0;
        __syncthreads();
        s[tid] += v;
        __syncthreads();
    }
    if (tid < nb) bsum[tid] = (tid > 0) ? s[tid - 1] : 0;
    if (tid == nb) bsum[nb] = s[nb - 1];
}

__global__ void k_scanC(const int* __restrict__ deg, int N, const int* __restrict__ bsum,
                        int* __restrict__ off){
    __shared__ int s[512];
    int b = blockIdx.x, tid = threadIdx.x;
    int i = b * 512 + tid;
    int v = (i < N) ? deg[i] : 0;
    s[tid] = v;
    __syncthreads();
    for (int o = 1; o < 512; o <<= 1){
        int t = (tid >= o) ? s[tid - o] : 0;
        __syncthreads();
        s[tid] += t;
        __syncthreads();
    }
    int ex = bsum[b] + ((tid > 0) ? s[tid - 1] : 0);
    if (i < N) off[i] = ex;
    else if (i == N) off[N] = ex;
}

__global__ void k_fill(const int* __restrict__ src, const int* __restrict__ dst, int E,
                       const int* __restrict__ off, int* __restrict__ cursor,
                       int* __restrict__ csr_src){
    int i = blockIdx.x*blockDim.x + threadIdx.x;
    if (i < E){
        int d = dst[i];
        int p = off[d] + atomicAdd(&cursor[d], 1);
        csr_src[p] = src[i];
    }
}

// ---------------- aggregation: 2 rows per wave, 16B/lane, 8-deep unroll ----------------
__global__ void k_agg(const unsigned short* __restrict__ h, const int* __restrict__ off,
                      const int* __restrict__ csr, unsigned short* __restrict__ out, int N){
    int wave = threadIdx.x >> 6, lane = threadIdx.x & 63;
    int d = blockIdx.x * 8 + wave * 2 + (lane >> 5);
    if (d >= N) return;
    int c = (lane & 31) * 8;
    float a[8] = {};
    int s0 = off[d], s1 = off[d + 1];
    int j = s0;
    for (; j + 7 < s1; j += 8){
        bf16x8 v[8];
        #pragma unroll
        for (int u = 0; u < 8; u++)
            v[u] = *(const bf16x8*)(h + (size_t)csr[j + u] * HID + c);
        #pragma unroll
        for (int u = 0; u < 8; u++)
            #pragma unroll
            for (int q = 0; q < 8; q++)
                a[q] += bf2f((unsigned short)v[u][q]);
    }
    for (; j + 1 < s1; j += 2){
        bf16x8 vA = *(const bf16x8*)(h + (size_t)csr[j] * HID + c);
        bf16x8 vB = *(const bf16x8*)(h + (size_t)csr[j + 1] * HID + c);
        #pragma unroll
        for (int q = 0; q < 8; q++)
            a[q] += bf2f((unsigned short)vA[q]) + bf2f((unsigned short)vB[q]);
    }
    if (j < s1){
        bf16x8 vA = *(const bf16x8*)(h + (size_t)csr[j] * HID + c);
        #pragma unroll
        for (int q = 0; q < 8; q++) a[q] += bf2f((unsigned short)vA[q]);
    }
    bf16x8 o;
    #pragma unroll
    for (int q = 0; q < 8; q++) o[q] = (short)f2bf(a[q]);
    *(bf16x8*)(out + (size_t)d * HID + c) = o;
}

// ---------------- GEMM body: C = A @ B^T, B is [N][K] row-major, bf16 ----------------
// BM=128, BN=128, BK=32; NB=3 buffers, ONE barrier per K-step, counted vmcnt.
__device__ __forceinline__ void gemm_body(unsigned short* sm,
    const unsigned short* __restrict__ A, const unsigned short* __restrict__ B,
    unsigned short* __restrict__ C, int M, int N, int K, long row0, int col0)
{
    const int tid = threadIdx.x, w = tid >> 6, l = tid & 63;
    const int wm = w >> 1, wn = w & 1, lr = l & 15, lk = l >> 4;

    long aoff0, aoff1, boff0, boff1;
    {
        int r0 = tid >> 2,          kc0 = tid & 3;
        int r1 = (tid + 256) >> 2,  kc1 = tid & 3;
        long g0 = row0 + r0; if (g0 > M - 1) g0 = M - 1;
        long g1 = row0 + r1; if (g1 > M - 1) g1 = M - 1;
        aoff0 = g0 * (long)K + (kc0 ^ ((r0 >> 1) & 3)) * 8;
        aoff1 = g1 * (long)K + (kc1 ^ ((r1 >> 1) & 3)) * 8;
        boff0 = (long)(col0 + r0) * K + (kc0 ^ ((r0 >> 1) & 3)) * 8;
        boff1 = (long)(col0 + r1) * K + (kc1 ^ ((r1 >> 1) & 3)) * 8;
    }
    auto STAGE = [&](int T, int buf){
        const int ka = T * 32;
        unsigned short* d = sm + (size_t)buf * 8192;
        gll16(A + aoff0 + ka, d + (0 * 256 + w * 64) * 8);
        gll16(A + aoff1 + ka, d + (1 * 256 + w * 64) * 8);
        gll16(B + boff0 + ka, d + (2 * 256 + w * 64) * 8);
        gll16(B + boff1 + ka, d + (3 * 256 + w * 64) * 8);
    };

    int raddrA[4], raddrB[4];
    #pragma unroll
    for (int i = 0; i < 4; i++){
        int ra = wm * 64 + i * 16 + lr;
        raddrA[i] = (ra * 4 + (lk ^ ((ra >> 1) & 3))) * 8;
        int rb = wn * 64 + i * 16 + lr;
        raddrB[i] = (512 + rb * 4 + (lk ^ ((rb >> 1) & 3))) * 8;
    }

    const int NT = K >> 5;
    STAGE(0, 0);
    STAGE(1, 1);

    f32x4 acc[4][4] = {};
    for (int t = 0; t < NT; t++){
        if (t < NT - 1) asm volatile("s_waitcnt vmcnt(4)" ::: "memory");
        else            asm volatile("s_waitcnt vmcnt(0)" ::: "memory");
        __builtin_amdgcn_s_barrier();
        if (t + 2 < NT) STAGE(t + 2, (t + 2) % 3);

        const unsigned short* bufp = sm + (size_t)(t % 3) * 8192;
        bf16x8 af[4], bfb[4];
        #pragma unroll
        for (int i = 0; i < 4; i++){
            af[i]  = *(const bf16x8*)(bufp + raddrA[i]);
            bfb[i] = *(const bf16x8*)(bufp + raddrB[i]);
        }
        __builtin_amdgcn_s_setprio(1);
        #pragma unroll
        for (int mi = 0; mi < 4; mi++)
            #pragma unroll
            for (int ni = 0; ni < 4; ni++)
                acc[mi][ni] = __builtin_amdgcn_mfma_f32_16x16x32_bf16(af[mi], bfb[ni], acc[mi][ni], 0, 0, 0);
        __builtin_amdgcn_s_setprio(0);
    }

    #pragma unroll
    for (int mi = 0; mi < 4; mi++)
        #pragma unroll
        for (int ni = 0; ni < 4; ni++)
            #pragma unroll
            for (int r = 0; r < 4; r++){
                long row = row0 + wm * 64 + mi * 16 + lk * 4 + r;
                if (row < M){
                    int col = col0 + wn * 64 + ni * 16 + lr;
                    C[row * (long)N + col] = f2bf(acc[mi][ni][r]);
                }
            }
}

// combined dispatch: blocks [0,36) = 3x Weff (W_ih @ Wg_l^T, 768x256), rest = h0 (x0 @ wproj^T)
__global__ __launch_bounds__(256, 3) void k_mmC(
    const unsigned short* __restrict__ x0, const unsigned short* __restrict__ wproj,
    unsigned short* __restrict__ hA, int Nn, int EMB,
    const unsigned short* __restrict__ wih, const unsigned short* __restrict__ wg,
    unsigned short* __restrict__ weff)
{
    __shared__ __align__(16) unsigned short sm[3 * 1024 * 8];
    size_t HH = (size_t)HID * HID;
    int orig = xcd_chunk(blockIdx.x, gridDim.x);
    if (orig < 36){
        int layer = orig / 12, sub = orig % 12;
        gemm_body(sm, wih, wg + layer * HH, weff + layer * 3 * HH,
                  3 * HID, HID, HID, (long)(sub >> 1) * 128, (sub & 1) * 128);
    } else {
        int sub = orig - 36;
        gemm_body(sm, x0, wproj, hA,
                  Nn, HID, EMB, (long)(sub >> 1) * 128, (sub & 1) * 128);
    }
}

// ---------------- fused GRU v13: virtual K=512, NB=2, 1-ahead, 4 blocks/CU ----------
// Block = 64 rows x 64 cols x {r,z,n} gate-sets; 4 waves, wave tile 32x32/set.
// tiles 0-7: A=AGG vs WE (aR,aZ,aI); tiles 8-15: A=H vs WH (aR,aZ,aHn).
// NB=2 x 16 KiB = 32 KiB LDS -> 5-block LDS ceiling; launch_bounds(256,4) -> 4 blocks/CU
// (16 waves). Schedule per step: {vmcnt(0); barrier; STAGE(t+1)->buf[(t+1)&1];
// ds_read buf[t&1]; MFMA}. Full drain is covered by cross-block overlap (blocks
// don't share barriers). WAR safe: barrier at t guarantees iter t-1's reads of
// buf[(t+1)&1] were consumed (lgkm waits precede that iter's MFMAs).
__global__ __launch_bounds__(256, 4) void k_gru(
    const unsigned short* __restrict__ AGG, const unsigned short* __restrict__ H,
    const unsigned short* __restrict__ WE, const unsigned short* __restrict__ WH,
    const float* __restrict__ bih, const float* __restrict__ bhh,
    unsigned short* __restrict__ HN, int M)
{
    __shared__ __align__(16) unsigned short sm[2 * 1024 * 8];   // 32 KiB
    const int tid = threadIdx.x, w = tid >> 6, l = tid & 63;
    const int wm = w >> 1, wn = w & 1, lr = l & 15, lk = l >> 4;
    const int orig = xcd_chunk(blockIdx.x, gridDim.x);
    const long row0 = (long)(orig >> 2) * 64;
    const int  c0 = (orig & 3) * 64;

    long aoff, boff[3];
    {
        int r0 = tid >> 2, kc = tid & 3;
        long g0 = row0 + r0; if (g0 > M - 1) g0 = M - 1;
        int sw = (kc ^ ((r0 >> 1) & 3)) * 8;
        aoff = g0 * HID + sw;
        #pragma unroll
        for (int q = 0; q < 3; q++)
            boff[q] = (long)(q * HID + c0 + r0) * HID + sw;
    }
    auto STAGE = [&](int T, int buf){
        const unsigned short* As = (T < 8) ? AGG : H;
        const unsigned short* Bs = (T < 8) ? WE  : WH;
        const int ka = (T & 7) * 32;
        unsigned short* d = sm + (size_t)buf * 8192;
        gll16(As + aoff + ka, d + (w * 64) * 8);
        #pragma unroll
        for (int q = 0; q < 3; q++)
            gll16(Bs + boff[q] + ka, d + (256 + q * 256 + w * 64) * 8);
    };

    int raddrA[2], raddrB[3][2];
    #pragma unroll
    for (int i = 0; i < 2; i++){
        int ra = wm * 32 + i * 16 + lr;
        raddrA[i] = (ra * 4 + (lk ^ ((ra >> 1) & 3))) * 8;
    }
    #pragma unroll
    for (int j = 0; j < 3; j++)
        #pragma unroll
        for (int ni = 0; ni < 2; ni++){
            int rb = wn * 32 + ni * 16 + lr;
            raddrB[j][ni] = (256 + j * 256 + rb * 4 + (lk ^ ((rb >> 1) & 3))) * 8;
        }

    f32x4 aR[2][2] = {}, aZ[2][2] = {}, aI[2][2] = {}, aHn[2][2] = {};

    STAGE(0, 0);

    #pragma unroll
    for (int t = 0; t < 16; t++){
        asm volatile("s_waitcnt vmcnt(0)" ::: "memory");
        __builtin_amdgcn_s_barrier();
        if (t + 1 < 16) STAGE(t + 1, (t + 1) & 1);

        const unsigned short* bufp = sm + (size_t)(t & 1) * 8192;
        bf16x8 a[2], bb[3][2];
        #pragma unroll
        for (int i = 0; i < 2; i++) a[i] = *(const bf16x8*)(bufp + raddrA[i]);
        #pragma unroll
        for (int j = 0; j < 3; j++)
            #pragma unroll
            for (int ni = 0; ni < 2; ni++)
                bb[j][ni] = *(const bf16x8*)(bufp + raddrB[j][ni]);

        __builtin_amdgcn_s_setprio(1);
        #pragma unroll
        for (int ni = 0; ni < 2; ni++)
            #pragma unroll
            for (int mi = 0; mi < 2; mi++){
                aR[mi][ni] = __builtin_amdgcn_mfma_f32_16x16x32_bf16(a[mi], bb[0][ni], aR[mi][ni], 0, 0, 0);
                aZ[mi][ni] = __builtin_amdgcn_mfma_f32_16x16x32_bf16(a[mi], bb[1][ni], aZ[mi][ni], 0, 0, 0);
                if (t < 8)
                    aI[mi][ni]  = __builtin_amdgcn_mfma_f32_16x16x32_bf16(a[mi], bb[2][ni], aI[mi][ni], 0, 0, 0);
                else
                    aHn[mi][ni] = __builtin_amdgcn_mfma_f32_16x16x32_bf16(a[mi], bb[2][ni], aHn[mi][ni], 0, 0, 0);
            }
        __builtin_amdgcn_s_setprio(0);
    }

    #pragma unroll
    for (int ni = 0; ni < 2; ni++){
        int gc = c0 + wn * 32 + ni * 16 + lr;
        float br  = bih[gc] + bhh[gc];
        float bz  = bih[HID + gc] + bhh[HID + gc];
        float bin = bih[2 * HID + gc];
        float bhn = bhh[2 * HID + gc];
        #pragma unroll
        for (int mi = 0; mi < 2; mi++)
            #pragma unroll
            for (int r = 0; r < 4; r++){
                long row = row0 + wm * 32 + mi * 16 + lk * 4 + r;
                if (row < M){
                    float rr = sigm(aR[mi][ni][r] + br);
                    float zz = sigm(aZ[mi][ni][r] + bz);
                    float nn = tanhf(aI[mi][ni][r] + bin + rr * (aHn[mi][ni][r] + bhn));
                    float hv = bf2f(H[row * HID + gc]);
                    HN[row * HID + gc] = f2bf((1.f - zz) * nn + zz * hv);
                }
            }
    }
}

// ---------------- pool phase 1: per-(graph, slice) partial max ----------------
__global__ void k_poolP(const unsigned short* __restrict__ h, const int* __restrict__ batch,
                        int Nn, int G, float* __restrict__ part){
    int g = blockIdx.x >> 3, slice = blockIdx.x & 7;
    int c = threadIdx.x;

    int lo = 0, hi = Nn;
    while (lo < hi){ int mid = (lo + hi) >> 1; if (batch[mid] < g) lo = mid + 1; else hi = mid; }
    int s = lo;
    lo = s; hi = Nn;
    while (lo < hi){ int mid = (lo + hi) >> 1; if (batch[mid] < g + 1) lo = mid + 1; else hi = mid; }
    int e = lo;

    int len = e - s;
    int rs = s + (int)(((long)len * slice) >> 3);
    int re = s + (int)(((long)len * (slice + 1)) >> 3);

    float mx = -INFINITY;
    for (int i = rs; i < re; i++) mx = fmaxf(mx, bf2f(h[(size_t)i * HID + c]));
    part[((size_t)blockIdx.x) * HID + c] = mx;
}

// ---------------- pool phase 2: reduce partials + MLP head ----------------
__global__ void k_mlp(const float* __restrict__ part, int G,
                      const float* __restrict__ W1, const float* __restrict__ b1,
                      const float* __restrict__ W2, const float* __restrict__ b2,
                      float* __restrict__ out){
    int g = blockIdx.x;
    int c = threadIdx.x;
    __shared__ float pool[HID];
    __shared__ float hid[64];

    float mx = -INFINITY;
    #pragma unroll
    for (int sl = 0; sl < 8; sl++)
        mx = fmaxf(mx, part[((size_t)(g * 8 + sl)) * HID + c]);
    pool[c] = mx;
    out[(size_t)G + (size_t)g * HID + c] = mx;
    __syncthreads();

    if (c < 64){
        float sacc = b1[c];
        for (int k = 0; k < HID; k++) sacc += pool[k] * W1[c * HID + k];
        hid[c] = fmaxf(sacc, 0.f) * W2[c];
    }
    __syncthreads();
    if (c == 0){
        float sacc = b2[0];
        for (int j = 0; j < 64; j++) sacc += hid[j];
        out[g] = sacc;
    }
}

extern "C" void kernel_launch(void* const* d_in, const int* in_sizes, int n_in,
                              void* d_out, int out_size, void* d_ws, size_t ws_size,
                              hipStream_t stream){
    const int*   x_lex = (const int*)d_in[0];
    const int*   edge  = (const int*)d_in[1];
    const int*   batch = (const int*)d_in[2];
    const float* embed = (const float*)d_in[3];
    const float* Wproj = (const float*)d_in[4];
    const float* Wg    = (const float*)d_in[5];
    const float* Wih   = (const float*)d_in[6];
    const float* bih   = (const float*)d_in[7];
    const float* Whh   = (const float*)d_in[8];
    const float* bhh   = (const float*)d_in[9];
    const float* W1    = (const float*)d_in[10];
    const float* b1    = (const float*)d_in[11];
    const float* W2    = (const float*)d_in[12];
    const float* b2    = (const float*)d_in[13];

    int Nn  = in_sizes[0];
    int E   = in_sizes[1] / 2;
    int G   = out_size / (1 + HID);
    int EMB = in_sizes[4] / HID;   // W_proj is [HID, EMBED]

    const int* esrc = edge;
    const int* edst = edge + E;

    size_t HH = (size_t)HID * HID;
    unsigned short* x0    = (unsigned short*)d_ws;
    unsigned short* hA    = x0    + (size_t)Nn * EMB;
    unsigned short* hB    = hA    + (size_t)Nn * HID;
    unsigned short* aggh  = hB    + (size_t)Nn * HID;
    unsigned short* wproj = aggh  + (size_t)Nn * HID;
    unsigned short* wih   = wproj + (size_t)HID * EMB;
    unsigned short* whh   = wih   + 3 * HH;
    unsigned short* wg    = whh   + 3 * HH;   // Wg natural row-major per layer
    unsigned short* weff  = wg    + 3 * HH;   // 3 layers x [768][256]
    int* deg    = (int*)(weff + 9 * HH);
    int* cursor = deg + Nn;
    int* off    = cursor + Nn;
    int* csr    = off + Nn + 1;
    int nbScan  = (Nn + 511) / 512;
    int* bsum   = csr + E;                    // nbScan + 1 ints
    float* part = (float*)(bsum + nbScan + 1);  // G*8*HID floats

    size_t ush = (size_t)Nn * (EMB + 3 * HID) + (size_t)HID * EMB + 18 * HH;
    size_t needed = ush * 2 + (size_t)(3 * Nn + 2 + E + nbScan + 1) * sizeof(int)
                  + (size_t)G * 8 * HID * sizeof(float);
    if (ws_size < needed) return;

    // merged weight casts + embed gather + degree histogram
    hipMemsetAsync(deg, 0, sizeof(int) * (size_t)(2 * Nn), stream);
    k_prep<<<2048, 256, 0, stream>>>(Wproj, Wih, Whh, Wg, embed, x_lex,
                                     edst, E, deg,
                                     wproj, wih, whh, wg, x0, Nn, EMB);
    k_scanA<<<nbScan, 512, 0, stream>>>(deg, Nn, bsum);
    k_scanB<<<1, 1024, 0, stream>>>(bsum, nbScan);
    k_scanC<<<(Nn + 512) / 512, 512, 0, stream>>>(deg, Nn, bsum, off);
    k_fill <<<(E + 255) / 256, 256, 0, stream>>>(esrc, edst, E, off, cursor, csr);

    int mb = (Nn + 127) / 128;

    // combined: 3x Weff (36 blocks) + h0 GEMM (mb*2 blocks) in one dispatch
    k_mmC<<<36 + mb * 2, 256, 0, stream>>>(x0, wproj, hA, Nn, EMB, wih, wg, weff);

    int gruBlocks = ((Nn + 63) / 64) * 4;

    unsigned short* hc = hA;
    unsigned short* hn = hB;
    for (int lay = 0; lay < 3; lay++){
        k_agg<<<(Nn + 7) / 8, 256, 0, stream>>>(hc, off, csr, aggh, Nn);
        k_gru<<<gruBlocks, 256, 0, stream>>>(
            aggh, hc, weff + (size_t)lay * 3 * HH, whh, bih, bhh, hn, Nn);
        unsigned short* t = hc; hc = hn; hn = t;
    }

    k_poolP<<<G * 8, HID, 0, stream>>>(hc, batch, Nn, G, part);
    k_mlp  <<<G, HID, 0, stream>>>(part, G, W1, b1, W2, b2, (float*)d_out);
}

// Round 14
// 527.957 us; speedup vs baseline: 1.0061x; 1.0061x over previous
//
#include <hip/hip_runtime.h>
#include <math.h>

constexpr int HID = 256;

typedef __attribute__((ext_vector_type(8))) short bf16x8;
typedef __attribute__((ext_vector_type(4))) float f32x4;

__device__ __forceinline__ float bf2f(unsigned short u){
    union { unsigned int i; float f; } v; v.i = ((unsigned int)u) << 16; return v.f;
}
__device__ __forceinline__ unsigned short f2bf(float f){
    union { float f; unsigned int i; } v; v.f = f;
    return (unsigned short)((v.i + 0x7fffu + ((v.i >> 16) & 1u)) >> 16);
}
__device__ __forceinline__ float sigm(float x){ return 1.f / (1.f + __expf(-x)); }

// bijective XCD-chunked swizzle (m204): consecutive ORIG ids land on the same XCD.
__device__ __forceinline__ int xcd_chunk(int bid, int nwg){
    int q = nwg >> 3, r = nwg & 7;
    int xcd = bid & 7, pos = bid >> 3;
    return (xcd < r) ? xcd * (q + 1) + pos : r * (q + 1) + (xcd - r) * q + pos;
}

// async global->LDS, 16B per lane. LDS dest is wave-uniform base; HW adds lane*16.
__device__ __forceinline__ void gll16(const unsigned short* g, unsigned short* l){
    __builtin_amdgcn_global_load_lds(
        (const __attribute__((address_space(1))) void*)g,
        (__attribute__((address_space(3))) void*)l, 16, 0, 0);
}

// ---------------- merged: weight casts + embedding gather + degree histogram ----------------
__global__ void k_prep(const float* __restrict__ Wproj, const float* __restrict__ Wih,
                       const float* __restrict__ Whh, const float* __restrict__ Wg,
                       const float* __restrict__ embed, const int* __restrict__ idx,
                       const int* __restrict__ edst, int E, int* __restrict__ deg,
                       unsigned short* __restrict__ wproj, unsigned short* __restrict__ wih,
                       unsigned short* __restrict__ whh, unsigned short* __restrict__ wg,
                       unsigned short* __restrict__ x0, int Nn, int EMB){
    const long n1 = (long)HID * EMB, n2 = 3L * HID * HID;
    const long n5 = (long)Nn * EMB;
    const long tot = n1 + 3 * n2 + n5 + E;
    for (long i = blockIdx.x * (long)blockDim.x + threadIdx.x; i < tot;
         i += (long)gridDim.x * blockDim.x){
        long j = i;
        if (j < n1){ wproj[j] = f2bf(Wproj[j]); continue; }
        j -= n1;
        if (j < n2){ wih[j] = f2bf(Wih[j]); continue; }
        j -= n2;
        if (j < n2){ whh[j] = f2bf(Whh[j]); continue; }
        j -= n2;
        if (j < n2){ wg[j] = f2bf(Wg[j]); continue; }
        j -= n2;
        if (j < n5){
            int row = (int)(j / EMB), k = (int)(j % EMB);
            x0[j] = f2bf(embed[(size_t)idx[row] * EMB + k]);
            continue;
        }
        j -= n5;
        atomicAdd(&deg[edst[j]], 1);
    }
}

// 3-phase parallel scan
__global__ void k_scanA(const int* __restrict__ deg, int N, int* __restrict__ bsum){
    __shared__ int red[512];
    int b = blockIdx.x, tid = threadIdx.x;
    int i = b * 512 + tid;
    red[tid] = (i < N) ? deg[i] : 0;
    __syncthreads();
    for (int o = 256; o > 0; o >>= 1){
        if (tid < o) red[tid] += red[tid + o];
        __syncthreads();
    }
    if (tid == 0) bsum[b] = red[0];
}

__global__ void k_scanB(int* __restrict__ bsum, int nb){
    __shared__ int s[1024];
    int tid = threadIdx.x;
    s[tid] = (tid < nb) ? bsum[tid] : 0;
    __syncthreads();
    for (int o = 1; o < 1024; o <<= 1){
        int v = (tid >= o) ? s[tid - o] : 0;
        __syncthreads();
        s[tid] += v;
        __syncthreads();
    }
    if (tid < nb) bsum[tid] = (tid > 0) ? s[tid - 1] : 0;
    if (tid == nb) bsum[nb] = s[nb - 1];
}

__global__ void k_scanC(const int* __restrict__ deg, int N, const int* __restrict__ bsum,
                        int* __restrict__ off){
    __shared__ int s[512];
    int b = blockIdx.x, tid = threadIdx.x;
    int i = b * 512 + tid;
    int v = (i < N) ? deg[i] : 0;
    s[tid] = v;
    __syncthreads();
    for (int o = 1; o < 512; o <<= 1){
        int t = (tid >= o) ? s[tid - o] : 0;
        __syncthreads();
        s[tid] += t;
        __syncthreads();
    }
    int ex = bsum[b] + ((tid > 0) ? s[tid - 1] : 0);
    if (i < N) off[i] = ex;
    else if (i == N) off[N] = ex;
}

__global__ void k_fill(const int* __restrict__ src, const int* __restrict__ dst, int E,
                       const int* __restrict__ off, int* __restrict__ cursor,
                       int* __restrict__ csr_src){
    int i = blockIdx.x*blockDim.x + threadIdx.x;
    if (i < E){
        int d = dst[i];
        int p = off[d] + atomicAdd(&cursor[d], 1);
        csr_src[p] = src[i];
    }
}

// ---------------- aggregation: 2 rows per wave, 16B/lane, 8-deep unroll ----------------
__global__ void k_agg(const unsigned short* __restrict__ h, const int* __restrict__ off,
                      const int* __restrict__ csr, unsigned short* __restrict__ out, int N){
    int wave = threadIdx.x >> 6, lane = threadIdx.x & 63;
    int d = blockIdx.x * 8 + wave * 2 + (lane >> 5);
    if (d >= N) return;
    int c = (lane & 31) * 8;
    float a[8] = {};
    int s0 = off[d], s1 = off[d + 1];
    int j = s0;
    for (; j + 7 < s1; j += 8){
        bf16x8 v[8];
        #pragma unroll
        for (int u = 0; u < 8; u++)
            v[u] = *(const bf16x8*)(h + (size_t)csr[j + u] * HID + c);
        #pragma unroll
        for (int u = 0; u < 8; u++)
            #pragma unroll
            for (int q = 0; q < 8; q++)
                a[q] += bf2f((unsigned short)v[u][q]);
    }
    for (; j + 1 < s1; j += 2){
        bf16x8 vA = *(const bf16x8*)(h + (size_t)csr[j] * HID + c);
        bf16x8 vB = *(const bf16x8*)(h + (size_t)csr[j + 1] * HID + c);
        #pragma unroll
        for (int q = 0; q < 8; q++)
            a[q] += bf2f((unsigned short)vA[q]) + bf2f((unsigned short)vB[q]);
    }
    if (j < s1){
        bf16x8 vA = *(const bf16x8*)(h + (size_t)csr[j] * HID + c);
        #pragma unroll
        for (int q = 0; q < 8; q++) a[q] += bf2f((unsigned short)vA[q]);
    }
    bf16x8 o;
    #pragma unroll
    for (int q = 0; q < 8; q++) o[q] = (short)f2bf(a[q]);
    *(bf16x8*)(out + (size_t)d * HID + c) = o;
}

// ---------------- GEMM body: C = A @ B^T, B is [N][K] row-major, bf16 ----------------
// BM=128, BN=128, BK=32; NB=3 buffers, ONE barrier per K-step, counted vmcnt.
__device__ __forceinline__ void gemm_body(unsigned short* sm,
    const unsigned short* __restrict__ A, const unsigned short* __restrict__ B,
    unsigned short* __restrict__ C, int M, int N, int K, long row0, int col0)
{
    const int tid = threadIdx.x, w = tid >> 6, l = tid & 63;
    const int wm = w >> 1, wn = w & 1, lr = l & 15, lk = l >> 4;

    long aoff0, aoff1, boff0, boff1;
    {
        int r0 = tid >> 2,          kc0 = tid & 3;
        int r1 = (tid + 256) >> 2,  kc1 = tid & 3;
        long g0 = row0 + r0; if (g0 > M - 1) g0 = M - 1;
        long g1 = row0 + r1; if (g1 > M - 1) g1 = M - 1;
        aoff0 = g0 * (long)K + (kc0 ^ ((r0 >> 1) & 3)) * 8;
        aoff1 = g1 * (long)K + (kc1 ^ ((r1 >> 1) & 3)) * 8;
        boff0 = (long)(col0 + r0) * K + (kc0 ^ ((r0 >> 1) & 3)) * 8;
        boff1 = (long)(col0 + r1) * K + (kc1 ^ ((r1 >> 1) & 3)) * 8;
    }
    auto STAGE = [&](int T, int buf){
        const int ka = T * 32;
        unsigned short* d = sm + (size_t)buf * 8192;
        gll16(A + aoff0 + ka, d + (0 * 256 + w * 64) * 8);
        gll16(A + aoff1 + ka, d + (1 * 256 + w * 64) * 8);
        gll16(B + boff0 + ka, d + (2 * 256 + w * 64) * 8);
        gll16(B + boff1 + ka, d + (3 * 256 + w * 64) * 8);
    };

    int raddrA[4], raddrB[4];
    #pragma unroll
    for (int i = 0; i < 4; i++){
        int ra = wm * 64 + i * 16 + lr;
        raddrA[i] = (ra * 4 + (lk ^ ((ra >> 1) & 3))) * 8;
        int rb = wn * 64 + i * 16 + lr;
        raddrB[i] = (512 + rb * 4 + (lk ^ ((rb >> 1) & 3))) * 8;
    }

    const int NT = K >> 5;
    STAGE(0, 0);
    STAGE(1, 1);

    f32x4 acc[4][4] = {};
    for (int t = 0; t < NT; t++){
        if (t < NT - 1) asm volatile("s_waitcnt vmcnt(4)" ::: "memory");
        else            asm volatile("s_waitcnt vmcnt(0)" ::: "memory");
        __builtin_amdgcn_s_barrier();
        if (t + 2 < NT) STAGE(t + 2, (t + 2) % 3);

        const unsigned short* bufp = sm + (size_t)(t % 3) * 8192;
        bf16x8 af[4], bfb[4];
        #pragma unroll
        for (int i = 0; i < 4; i++){
            af[i]  = *(const bf16x8*)(bufp + raddrA[i]);
            bfb[i] = *(const bf16x8*)(bufp + raddrB[i]);
        }
        __builtin_amdgcn_s_setprio(1);
        #pragma unroll
        for (int mi = 0; mi < 4; mi++)
            #pragma unroll
            for (int ni = 0; ni < 4; ni++)
                acc[mi][ni] = __builtin_amdgcn_mfma_f32_16x16x32_bf16(af[mi], bfb[ni], acc[mi][ni], 0, 0, 0);
        __builtin_amdgcn_s_setprio(0);
    }

    #pragma unroll
    for (int mi = 0; mi < 4; mi++)
        #pragma unroll
        for (int ni = 0; ni < 4; ni++)
            #pragma unroll
            for (int r = 0; r < 4; r++){
                long row = row0 + wm * 64 + mi * 16 + lk * 4 + r;
                if (row < M){
                    int col = col0 + wn * 64 + ni * 16 + lr;
                    C[row * (long)N + col] = f2bf(acc[mi][ni][r]);
                }
            }
}

// combined dispatch: blocks [0,36) = 3x Weff (W_ih @ Wg_l^T, 768x256), rest = h0 (x0 @ wproj^T)
__global__ __launch_bounds__(256, 3) void k_mmC(
    const unsigned short* __restrict__ x0, const unsigned short* __restrict__ wproj,
    unsigned short* __restrict__ hA, int Nn, int EMB,
    const unsigned short* __restrict__ wih, const unsigned short* __restrict__ wg,
    unsigned short* __restrict__ weff)
{
    __shared__ __align__(16) unsigned short sm[3 * 1024 * 8];
    size_t HH = (size_t)HID * HID;
    int orig = xcd_chunk(blockIdx.x, gridDim.x);
    if (orig < 36){
        int layer = orig / 12, sub = orig % 12;
        gemm_body(sm, wih, wg + layer * HH, weff + layer * 3 * HH,
                  3 * HID, HID, HID, (long)(sub >> 1) * 128, (sub & 1) * 128);
    } else {
        int sub = orig - 36;
        gemm_body(sm, x0, wproj, hA,
                  Nn, HID, EMB, (long)(sub >> 1) * 128, (sub & 1) * 128);
    }
}

// ---------------- fused GRU (round-12/8 proven version): virtual K=512, gll16 NB=3 ----------
// Block = 64 rows x 64 cols x {r,z,n} gate-sets; 4 waves, wave tile 32x32/set.
// tiles 0-7: A=AGG vs WE (aR,aZ,aI); tiles 8-15: A=H vs WH (aR,aZ,aHn).
// NB=3 x 16 KiB LDS = 48 KiB; counted vmcnt(4); ONE barrier per tile.
// NOTE (r13 A/B): NB=2 + 4 blocks/CU + full drain = 82.2us; this NB=3 + ~2.2 blocks = 81.0us.
// Occupancy-invariant => 2-barrier template's latency ceiling for this shape (~476 TF eff).
__global__ __launch_bounds__(256, 3) void k_gru(
    const unsigned short* __restrict__ AGG, const unsigned short* __restrict__ H,
    const unsigned short* __restrict__ WE, const unsigned short* __restrict__ WH,
    const float* __restrict__ bih, const float* __restrict__ bhh,
    unsigned short* __restrict__ HN, int M)
{
    __shared__ __align__(16) unsigned short sm[3 * 1024 * 8];
    const int tid = threadIdx.x, w = tid >> 6, l = tid & 63;
    const int wm = w >> 1, wn = w & 1, lr = l & 15, lk = l >> 4;
    const int orig = xcd_chunk(blockIdx.x, gridDim.x);
    const long row0 = (long)(orig >> 2) * 64;
    const int  c0 = (orig & 3) * 64;

    long aoff, boff[3];
    {
        int r0 = tid >> 2, kc = tid & 3;
        long g0 = row0 + r0; if (g0 > M - 1) g0 = M - 1;
        int sw = (kc ^ ((r0 >> 1) & 3)) * 8;
        aoff = g0 * HID + sw;
        #pragma unroll
        for (int q = 0; q < 3; q++)
            boff[q] = (long)(q * HID + c0 + r0) * HID + sw;
    }
    auto STAGE = [&](int T, int buf){
        const unsigned short* As = (T < 8) ? AGG : H;
        const unsigned short* Bs = (T < 8) ? WE  : WH;
        const int ka = (T & 7) * 32;
        unsigned short* d = sm + (size_t)buf * 8192;
        gll16(As + aoff + ka, d + (w * 64) * 8);
        #pragma unroll
        for (int q = 0; q < 3; q++)
            gll16(Bs + boff[q] + ka, d + (256 + q * 256 + w * 64) * 8);
    };

    int raddrA[2], raddrB[3][2];
    #pragma unroll
    for (int i = 0; i < 2; i++){
        int ra = wm * 32 + i * 16 + lr;
        raddrA[i] = (ra * 4 + (lk ^ ((ra >> 1) & 3))) * 8;
    }
    #pragma unroll
    for (int j = 0; j < 3; j++)
        #pragma unroll
        for (int ni = 0; ni < 2; ni++){
            int rb = wn * 32 + ni * 16 + lr;
            raddrB[j][ni] = (256 + j * 256 + rb * 4 + (lk ^ ((rb >> 1) & 3))) * 8;
        }

    f32x4 aR[2][2] = {}, aZ[2][2] = {}, aI[2][2] = {}, aHn[2][2] = {};

    STAGE(0, 0);
    STAGE(1, 1);

    #pragma unroll
    for (int t = 0; t < 16; t++){
        if (t < 15) asm volatile("s_waitcnt vmcnt(4)" ::: "memory");
        else        asm volatile("s_waitcnt vmcnt(0)" ::: "memory");
        __builtin_amdgcn_s_barrier();
        if (t + 2 < 16) STAGE(t + 2, (t + 2) % 3);

        const unsigned short* bufp = sm + (size_t)(t % 3) * 8192;
        bf16x8 a[2], bb[3][2];
        #pragma unroll
        for (int i = 0; i < 2; i++) a[i] = *(const bf16x8*)(bufp + raddrA[i]);
        #pragma unroll
        for (int j = 0; j < 3; j++)
            #pragma unroll
            for (int ni = 0; ni < 2; ni++)
                bb[j][ni] = *(const bf16x8*)(bufp + raddrB[j][ni]);

        __builtin_amdgcn_s_setprio(1);
        #pragma unroll
        for (int ni = 0; ni < 2; ni++)
            #pragma unroll
            for (int mi = 0; mi < 2; mi++){
                aR[mi][ni] = __builtin_amdgcn_mfma_f32_16x16x32_bf16(a[mi], bb[0][ni], aR[mi][ni], 0, 0, 0);
                aZ[mi][ni] = __builtin_amdgcn_mfma_f32_16x16x32_bf16(a[mi], bb[1][ni], aZ[mi][ni], 0, 0, 0);
                if (t < 8)
                    aI[mi][ni]  = __builtin_amdgcn_mfma_f32_16x16x32_bf16(a[mi], bb[2][ni], aI[mi][ni], 0, 0, 0);
                else
                    aHn[mi][ni] = __builtin_amdgcn_mfma_f32_16x16x32_bf16(a[mi], bb[2][ni], aHn[mi][ni], 0, 0, 0);
            }
        __builtin_amdgcn_s_setprio(0);
    }

    #pragma unroll
    for (int ni = 0; ni < 2; ni++){
        int gc = c0 + wn * 32 + ni * 16 + lr;
        float br  = bih[gc] + bhh[gc];
        float bz  = bih[HID + gc] + bhh[HID + gc];
        float bin = bih[2 * HID + gc];
        float bhn = bhh[2 * HID + gc];
        #pragma unroll
        for (int mi = 0; mi < 2; mi++)
            #pragma unroll
            for (int r = 0; r < 4; r++){
                long row = row0 + wm * 32 + mi * 16 + lk * 4 + r;
                if (row < M){
                    float rr = sigm(aR[mi][ni][r] + br);
                    float zz = sigm(aZ[mi][ni][r] + bz);
                    float nn = tanhf(aI[mi][ni][r] + bin + rr * (aHn[mi][ni][r] + bhn));
                    float hv = bf2f(H[row * HID + gc]);
                    HN[row * HID + gc] = f2bf((1.f - zz) * nn + zz * hv);
                }
            }
    }
}

// ---------------- pool phase 1: per-(graph, slice) partial max ----------------
__global__ void k_poolP(const unsigned short* __restrict__ h, const int* __restrict__ batch,
                        int Nn, int G, float* __restrict__ part){
    int g = blockIdx.x >> 3, slice = blockIdx.x & 7;
    int c = threadIdx.x;

    int lo = 0, hi = Nn;
    while (lo < hi){ int mid = (lo + hi) >> 1; if (batch[mid] < g) lo = mid + 1; else hi = mid; }
    int s = lo;
    lo = s; hi = Nn;
    while (lo < hi){ int mid = (lo + hi) >> 1; if (batch[mid] < g + 1) lo = mid + 1; else hi = mid; }
    int e = lo;

    int len = e - s;
    int rs = s + (int)(((long)len * slice) >> 3);
    int re = s + (int)(((long)len * (slice + 1)) >> 3);

    float mx = -INFINITY;
    for (int i = rs; i < re; i++) mx = fmaxf(mx, bf2f(h[(size_t)i * HID + c]));
    part[((size_t)blockIdx.x) * HID + c] = mx;
}

// ---------------- pool phase 2: reduce partials + MLP head ----------------
__global__ void k_mlp(const float* __restrict__ part, int G,
                      const float* __restrict__ W1, const float* __restrict__ b1,
                      const float* __restrict__ W2, const float* __restrict__ b2,
                      float* __restrict__ out){
    int g = blockIdx.x;
    int c = threadIdx.x;
    __shared__ float pool[HID];
    __shared__ float hid[64];

    float mx = -INFINITY;
    #pragma unroll
    for (int sl = 0; sl < 8; sl++)
        mx = fmaxf(mx, part[((size_t)(g * 8 + sl)) * HID + c]);
    pool[c] = mx;
    out[(size_t)G + (size_t)g * HID + c] = mx;
    __syncthreads();

    if (c < 64){
        float sacc = b1[c];
        for (int k = 0; k < HID; k++) sacc += pool[k] * W1[c * HID + k];
        hid[c] = fmaxf(sacc, 0.f) * W2[c];
    }
    __syncthreads();
    if (c == 0){
        float sacc = b2[0];
        for (int j = 0; j < 64; j++) sacc += hid[j];
        out[g] = sacc;
    }
}

extern "C" void kernel_launch(void* const* d_in, const int* in_sizes, int n_in,
                              void* d_out, int out_size, void* d_ws, size_t ws_size,
                              hipStream_t stream){
    const int*   x_lex = (const int*)d_in[0];
    const int*   edge  = (const int*)d_in[1];
    const int*   batch = (const int*)d_in[2];
    const float* embed = (const float*)d_in[3];
    const float* Wproj = (const float*)d_in[4];
    const float* Wg    = (const float*)d_in[5];
    const float* Wih   = (const float*)d_in[6];
    const float* bih   = (const float*)d_in[7];
    const float* Whh   = (const float*)d_in[8];
    const float* bhh   = (const float*)d_in[9];
    const float* W1    = (const float*)d_in[10];
    const float* b1    = (const float*)d_in[11];
    const float* W2    = (const float*)d_in[12];
    const float* b2    = (const float*)d_in[13];

    int Nn  = in_sizes[0];
    int E   = in_sizes[1] / 2;
    int G   = out_size / (1 + HID);
    int EMB = in_sizes[4] / HID;   // W_proj is [HID, EMBED]

    const int* esrc = edge;
    const int* edst = edge + E;

    size_t HH = (size_t)HID * HID;
    unsigned short* x0    = (unsigned short*)d_ws;
    unsigned short* hA    = x0    + (size_t)Nn * EMB;
    unsigned short* hB    = hA    + (size_t)Nn * HID;
    unsigned short* aggh  = hB    + (size_t)Nn * HID;
    unsigned short* wproj = aggh  + (size_t)Nn * HID;
    unsigned short* wih   = wproj + (size_t)HID * EMB;
    unsigned short* whh   = wih   + 3 * HH;
    unsigned short* wg    = whh   + 3 * HH;   // Wg natural row-major per layer
    unsigned short* weff  = wg    + 3 * HH;   // 3 layers x [768][256]
    int* deg    = (int*)(weff + 9 * HH);
    int* cursor = deg + Nn;
    int* off    = cursor + Nn;
    int* csr    = off + Nn + 1;
    int nbScan  = (Nn + 511) / 512;
    int* bsum   = csr + E;                    // nbScan + 1 ints
    float* part = (float*)(bsum + nbScan + 1);  // G*8*HID floats

    size_t ush = (size_t)Nn * (EMB + 3 * HID) + (size_t)HID * EMB + 18 * HH;
    size_t needed = ush * 2 + (size_t)(3 * Nn + 2 + E + nbScan + 1) * sizeof(int)
                  + (size_t)G * 8 * HID * sizeof(float);
    if (ws_size < needed) return;

    // merged weight casts + embed gather + degree histogram
    hipMemsetAsync(deg, 0, sizeof(int) * (size_t)(2 * Nn), stream);
    k_prep<<<2048, 256, 0, stream>>>(Wproj, Wih, Whh, Wg, embed, x_lex,
                                     edst, E, deg,
                                     wproj, wih, whh, wg, x0, Nn, EMB);
    k_scanA<<<nbScan, 512, 0, stream>>>(deg, Nn, bsum);
    k_scanB<<<1, 1024, 0, stream>>>(bsum, nbScan);
    k_scanC<<<(Nn + 512) / 512, 512, 0, stream>>>(deg, Nn, bsum, off);
    k_fill <<<(E + 255) / 256, 256, 0, stream>>>(esrc, edst, E, off, cursor, csr);

    int mb = (Nn + 127) / 128;

    // combined: 3x Weff (36 blocks) + h0 GEMM (mb*2 blocks) in one dispatch
    k_mmC<<<36 + mb * 2, 256, 0, stream>>>(x0, wproj, hA, Nn, EMB, wih, wg, weff);

    int gruBlocks = ((Nn + 63) / 64) * 4;

    unsigned short* hc = hA;
    unsigned short* hn = hB;
    for (int lay = 0; lay < 3; lay++){
        k_agg<<<(Nn + 7) / 8, 256, 0, stream>>>(hc, off, csr, aggh, Nn);
        k_gru<<<gruBlocks, 256, 0, stream>>>(
            aggh, hc, weff + (size_t)lay * 3 * HH, whh, bih, bhh, hn, Nn);
        unsigned short* t = hc; hc = hn; hn = t;
    }

    k_poolP<<<G * 8, HID, 0, stream>>>(hc, batch, Nn, G, part);
    k_mlp  <<<G, HID, 0, stream>>>(part, G, W1, b1, W2, b2, (float*)d_out);
}